// Round 6
// baseline (1065.445 us; speedup 1.0000x reference)
//
#include <hip/hip_runtime.h>
#include <hip/hip_bf16.h>

// Problem dims
#define NNODE 32
#define NB    64
#define NDIM  32
#define NSTEP 8
#define NE    992
#define NTT   16

typedef __bf16 bf16;
typedef __attribute__((ext_vector_type(8))) __bf16 bf16x8;
typedef __attribute__((ext_vector_type(4))) __bf16 bf16x4;
typedef __attribute__((ext_vector_type(4))) float  f32x4;

__device__ __forceinline__ f32x4 mfma_bf16(bf16x8 a, bf16x8 b, f32x4 c) {
  return __builtin_amdgcn_mfma_f32_16x16x32_bf16(a, b, c, 0, 0, 0);
}
__device__ __forceinline__ float sigm(float x) { return 1.0f / (1.0f + __expf(-x)); }
__device__ __forceinline__ float tanh_f(float x) {
  x = fminf(fmaxf(x, -15.0f), 15.0f);
  float e = __expf(2.0f * x);
  return (e - 1.0f) / (e + 1.0f);
}

// ---------------------------------------------------------------------------
// Swizzle [3][64][64] float weights into MFMA B-fragment bf16 order.
// Lane L of frag holds B[kf*32+(L>>4)*8+j][n], n per layout below.
// ---------------------------------------------------------------------------
__global__ void prep_weights(const float* __restrict__ W1, const float* __restrict__ W2,
                             const float* __restrict__ Wi, const float* __restrict__ Wh,
                             bf16* __restrict__ B1, bf16* __restrict__ B2,
                             bf16* __restrict__ GI, bf16* __restrict__ GH) {
  int u = blockIdx.x * 256 + threadIdx.x;
  if (u >= 12288) return;
  int k = u >> 12, i = (u >> 6) & 63, h = u & 63;
  int kf = i >> 5, quad = (i >> 3) & 3, j = i & 7;
  {
    int nn = k * 64 + h;                 // flat N (192) for W1/GI/GH
    int nt = nn >> 4;
    int lane = quad * 16 + (nn & 15);
    int slot = ((nt * 2 + kf) * 64 + lane) * 8 + j;
    B1[slot] = (bf16)W1[u];
    GI[slot] = (bf16)Wi[u];
    GH[slot] = (bf16)Wh[u];
  }
  {
    int ntl = h >> 4;                    // per-type N=64 for W2
    int lane = quad * 16 + (h & 15);
    int slot = k * 4096 + ((ntl * 2 + kf) * 64 + lane) * 8 + j;
    B2[slot] = (bf16)W2[u];
  }
}

// Load ground-truth step t into x_cur (fp32 + bf16 mirrors). Layout [n][b][d].
__global__ void copy_x(const float* __restrict__ x, float* __restrict__ xf,
                       bf16* __restrict__ xb, int t) {
  int u = blockIdx.x * 256 + threadIdx.x;  // 65536
  int n = u >> 11, b = (u >> 5) & 63, d = u & 31;
  float v = x[((b * 32 + n) * 32 + d) * 8 + t];
  xf[u] = v;
  xb[u] = (bf16)v;
}

// ---------------------------------------------------------------------------
// Edge step v2: one edge per block. msg MLP mixture + edge GRU, h_edge bf16
// in global. LDS 35.6 KB -> 4 blocks/CU. All staging coalesced 16B.
// ---------------------------------------------------------------------------
__global__ __launch_bounds__(256) void edge_step(
    const bf16* __restrict__ xb, const int* __restrict__ es,
    const float* __restrict__ z,
    const bf16* __restrict__ B1, const bf16* __restrict__ B2,
    const float* __restrict__ mb1, const float* __restrict__ mb2,
    const bf16* __restrict__ GI, const bf16* __restrict__ GH,
    const float* __restrict__ gbi, const float* __restrict__ gbh,
    bf16* __restrict__ hed, int t) {
  __shared__ __align__(16) bf16 A[64][72];     // inputs; then mix (Am); then out
  __shared__ __align__(16) bf16 A2[64][200];   // h1 (192 cols)
  __shared__ float zL[64][3];
  int e = blockIdx.x, tid = threadIdx.x;
  int ccol = es[e];        // aggregation target (block-contiguous: e/31)
  int crow = es[NE + e];   // msg = [x[row], x[col]]
  const bf16* s0 = xb + crow * 2048;
  const bf16* s1 = xb + ccol * 2048;
  // stage A: 512 chunks of 8 bf16, fully coalesced
  {
    int c = tid;
    int b = c >> 3, i8 = c & 7;
    const bf16* src = (i8 < 4) ? (s0 + b * 32 + i8 * 8) : (s1 + b * 32 + (i8 - 4) * 8);
    *(bf16x8*)&A[b][i8 * 8] = *(const bf16x8*)src;
    c = tid + 256; b = c >> 3; i8 = c & 7;
    src = (i8 < 4) ? (s0 + b * 32 + i8 * 8) : (s1 + b * 32 + (i8 - 4) * 8);
    *(bf16x8*)&A[b][i8 * 8] = *(const bf16x8*)src;
  }
  if (tid < 192) { int b = tid / 3, k = tid - b * 3; zL[b][k] = z[(b * NE + e) * 3 + k]; }
  __syncthreads();
  int wv = tid >> 6, ln = tid & 63, quad = ln >> 4, l16 = ln & 15;
  int m = wv * 16 + l16;
  bf16x8 af0 = *(const bf16x8*)&A[m][quad * 8];
  bf16x8 af1 = *(const bf16x8*)&A[m][32 + quad * 8];
  // ---- layer 1: [64x64] @ [64x192] ----
  f32x4 acc[12];
#pragma unroll
  for (int q = 0; q < 12; q++) { f32x4 zz = {0.f, 0.f, 0.f, 0.f}; acc[q] = zz; }
#pragma unroll
  for (int nt = 0; nt < 12; nt++) {
    bf16x8 w0 = *(const bf16x8*)&B1[(nt * 2 + 0) * 512 + ln * 8];
    bf16x8 w1 = *(const bf16x8*)&B1[(nt * 2 + 1) * 512 + ln * 8];
    acc[nt] = mfma_bf16(af0, w0, acc[nt]);
    acc[nt] = mfma_bf16(af1, w1, acc[nt]);
  }
#pragma unroll
  for (int nt = 0; nt < 12; nt++) {
    int n = nt * 16 + l16;
    float bias = mb1[n];
#pragma unroll
    for (int r = 0; r < 4; r++) {
      float v = acc[nt][r] + bias;
      A2[wv * 16 + quad * 4 + r][n] = (bf16)(v > 0.f ? v : 0.f);
    }
  }
  __syncthreads();
  // ---- layer 2: per-type [64x64] blocks ----
  bf16x8 a2[3][2];
#pragma unroll
  for (int kt = 0; kt < 3; kt++)
#pragma unroll
    for (int kf = 0; kf < 2; kf++)
      a2[kt][kf] = *(const bf16x8*)&A2[m][kt * 64 + kf * 32 + quad * 8];
  f32x4 acc2[12];
#pragma unroll
  for (int q = 0; q < 12; q++) { f32x4 zz = {0.f, 0.f, 0.f, 0.f}; acc2[q] = zz; }
#pragma unroll
  for (int kt = 0; kt < 3; kt++)
#pragma unroll
    for (int nt = 0; nt < 4; nt++) {
      bf16x8 w0 = *(const bf16x8*)&B2[kt * 4096 + (nt * 2 + 0) * 512 + ln * 8];
      bf16x8 w1 = *(const bf16x8*)&B2[kt * 4096 + (nt * 2 + 1) * 512 + ln * 8];
      acc2[kt * 4 + nt] = mfma_bf16(a2[kt][0], w0, acc2[kt * 4 + nt]);
      acc2[kt * 4 + nt] = mfma_bf16(a2[kt][1], w1, acc2[kt * 4 + nt]);
    }
  // ---- mix with z, /K ----
  float mix[4][4];
#pragma unroll
  for (int r = 0; r < 4; r++) {
    int b = wv * 16 + quad * 4 + r;
    float z0 = zL[b][0], z1 = zL[b][1], z2 = zL[b][2];
#pragma unroll
    for (int nt = 0; nt < 4; nt++) {
      int o = nt * 16 + l16;
      float h0 = acc2[nt][r]     + mb2[o];       h0 = h0 > 0.f ? h0 : 0.f;
      float h1 = acc2[4 + nt][r] + mb2[64 + o];  h1 = h1 > 0.f ? h1 : 0.f;
      float h2 = acc2[8 + nt][r] + mb2[128 + o]; h2 = h2 > 0.f ? h2 : 0.f;
      mix[r][nt] = (h0 * z0 + h1 * z1 + h2 * z2) * (1.0f / 3.0f);
    }
  }
  if (t == 0) {
    // state = mix
#pragma unroll
    for (int r = 0; r < 4; r++)
#pragma unroll
      for (int nt = 0; nt < 4; nt++)
        A[wv * 16 + quad * 4 + r][nt * 16 + l16] = (bf16)mix[r][nt];
  } else {
    // stage mix as GRU A-operand (own 16-row slice per wave)
#pragma unroll
    for (int r = 0; r < 4; r++)
#pragma unroll
      for (int nt = 0; nt < 4; nt++)
        A[wv * 16 + quad * 4 + r][nt * 16 + l16] = (bf16)mix[r][nt];
    __syncthreads();
    bf16x8 ai0 = *(const bf16x8*)&A[m][quad * 8];
    bf16x8 ai1 = *(const bf16x8*)&A[m][32 + quad * 8];
    const bf16* hrow = hed + e * 4096 + m * 64;
    bf16x8 ah0 = *(const bf16x8*)(hrow + quad * 8);
    bf16x8 ah1 = *(const bf16x8*)(hrow + 32 + quad * 8);
    f32x4 gi[12], gh[12];
#pragma unroll
    for (int q = 0; q < 12; q++) { f32x4 zz = {0.f, 0.f, 0.f, 0.f}; gi[q] = zz; gh[q] = zz; }
#pragma unroll
    for (int nt = 0; nt < 12; nt++) {
      bf16x8 wi0 = *(const bf16x8*)&GI[(nt * 2 + 0) * 512 + ln * 8];
      bf16x8 wi1 = *(const bf16x8*)&GI[(nt * 2 + 1) * 512 + ln * 8];
      bf16x8 wh0 = *(const bf16x8*)&GH[(nt * 2 + 0) * 512 + ln * 8];
      bf16x8 wh1 = *(const bf16x8*)&GH[(nt * 2 + 1) * 512 + ln * 8];
      gi[nt] = mfma_bf16(ai0, wi0, gi[nt]);
      gi[nt] = mfma_bf16(ai1, wi1, gi[nt]);
      gh[nt] = mfma_bf16(ah0, wh0, gh[nt]);
      gh[nt] = mfma_bf16(ah1, wh1, gh[nt]);
    }
#pragma unroll
    for (int r = 0; r < 4; r++) {
      int b = wv * 16 + quad * 4 + r;
#pragma unroll
      for (int nt = 0; nt < 4; nt++) {
        int o = nt * 16 + l16;
        float xr = gi[nt][r]     + gbi[o]       + gh[nt][r]     + gbh[o];
        float xi = gi[4 + nt][r] + gbi[64 + o]  + gh[4 + nt][r] + gbh[64 + o];
        float xn = gi[8 + nt][r] + gbi[128 + o];
        float hn = gh[8 + nt][r] + gbh[128 + o];
        float rg = sigm(xr);
        float ig = sigm(xi);
        float ng = tanh_f(xn + rg * hn);
        float hv = (float)hed[e * 4096 + b * 64 + o];
        A[b][o] = (bf16)((1.0f - ig) * ng + ig * hv);  // own-slice overwrite
      }
    }
  }
  __syncthreads();
  // coalesced writeback of new state
  {
    int c = tid;
    int b = c >> 3, j = c & 7;
    *(bf16x8*)(hed + e * 4096 + b * 64 + j * 8) = *(const bf16x8*)&A[b][j * 8];
    c = tid + 256; b = c >> 3; j = c & 7;
    *(bf16x8*)(hed + e * 4096 + b * 64 + j * 8) = *(const bf16x8*)&A[b][j * 8];
  }
}

// ---------------------------------------------------------------------------
// Node side (validated round-3 structure): scatter-mean agg (bf16 state) +
// GRU(96) scalar + 3-layer MLP head. 128 blocks x 256.
// ---------------------------------------------------------------------------
__global__ __launch_bounds__(256) void node_kernel(
    const float* __restrict__ x, const bf16* __restrict__ hed,
    float* __restrict__ xf, bf16* __restrict__ xbo, float* __restrict__ hnode,
    const float* __restrict__ gnWi, const float* __restrict__ gnbi,
    const float* __restrict__ gnWh, const float* __restrict__ gnbh,
    const float* __restrict__ oW1, const float* __restrict__ ob1,
    const float* __restrict__ oW2, const float* __restrict__ ob2,
    const float* __restrict__ oW3, const float* __restrict__ ob3,
    float* __restrict__ out, int t, int use_gru) {
  __shared__ float c0[4][96];
  __shared__ float cn[4][96];
  __shared__ float hv[4][96];
  __shared__ float s1[4][64];
  __shared__ float s2[4][64];
  int tid = threadIdx.x, wv = tid >> 6, ln = tid & 63;
  int row = blockIdx.x * 4 + wv;  // 0..511 -> row = n*64+b? No: grid 512 blocks? see launch
  int n = row >> 6, b = row & 63;
  // aggregation: mean over node n's 31 contiguous edges, this (b, o-range)
  // each lane covers o = ln (one column), 31 edges
  float aggv = 0.f;
  {
    const bf16* p = hed + (size_t)n * 31 * 4096 + b * 64 + ln;
#pragma unroll
    for (int e2 = 0; e2 < 31; e2++) aggv += (float)p[e2 * 4096];
    aggv *= (1.0f / 31.0f);
  }
  float xin = 0.0f;
  if (ln < 32) {
    xin = (t < NSTEP) ? x[((b * 32 + n) * 32 + ln) * 8 + t] : xf[n * 2048 + b * 32 + ln];
    c0[wv][ln] = xin;
  }
  c0[wv][32 + ln] = aggv;
  if (use_gru) {
    hv[wv][ln] = hnode[row * 96 + ln];
    if (ln < 32) hv[wv][64 + ln] = hnode[row * 96 + 64 + ln];
  }
  __syncthreads();
  if (use_gru) {
    for (int c = ln; c < 96; c += 64) {
      float si0 = gnbi[c],       sh0 = gnbh[c];
      float si1 = gnbi[96 + c],  sh1 = gnbh[96 + c];
      float si2 = gnbi[192 + c], sh2 = gnbh[192 + c];
      for (int i = 0; i < 96; i++) {
        float cv = c0[wv][i], hh = hv[wv][i];
        si0 += cv * gnWi[i * 96 + c];
        sh0 += hh * gnWh[i * 96 + c];
        si1 += cv * gnWi[(96 + i) * 96 + c];
        sh1 += hh * gnWh[(96 + i) * 96 + c];
        si2 += cv * gnWi[(192 + i) * 96 + c];
        sh2 += hh * gnWh[(192 + i) * 96 + c];
      }
      float rg = sigm(si0 + sh0);
      float ig = sigm(si1 + sh1);
      float ng = tanh_f(si2 + rg * sh2);
      float v = (1.0f - ig) * ng + ig * hv[wv][c];
      cn[wv][c] = v;
      hnode[row * 96 + c] = v;
    }
  } else {
    for (int c = ln; c < 96; c += 64) {
      float v = c0[wv][c];
      cn[wv][c] = v;
      hnode[row * 96 + c] = v;
    }
  }
  __syncthreads();
  {
    float a = ob1[ln];
    for (int i = 0; i < 96; i++) a += cn[wv][i] * oW1[i * 64 + ln];
    s1[wv][ln] = a > 0.f ? a : 0.f;
  }
  __syncthreads();
  {
    float a = ob2[ln];
    for (int i = 0; i < 64; i++) a += s1[wv][i] * oW2[i * 64 + ln];
    s2[wv][ln] = a > 0.f ? a : 0.f;
  }
  __syncthreads();
  if (ln < 32) {
    float a = ob3[ln];
    for (int i = 0; i < 64; i++) a += s2[wv][i] * oW3[i * 32 + ln];
    float xm = xin + a;
    xf[n * 2048 + b * 32 + ln] = xm;
    xbo[n * 2048 + b * 32 + ln] = (bf16)xm;
    int base = (b * 32 + n) * 32 + ln;
    out[524288 + base * 16 + t]  = xm;   // x_hat (copy 1)
    out[1572864 + base * 16 + t] = xm;   // x_hat (copy 2)
    if (t >= NSTEP) out[base * 8 + (t - NSTEP)] = xm;  // prediction window
  }
}

extern "C" void kernel_launch(void* const* d_in, const int* in_sizes, int n_in,
                              void* d_out, int out_size, void* d_ws, size_t ws_size,
                              hipStream_t stream) {
  const float* x     = (const float*)d_in[0];
  const float* z     = (const float*)d_in[1];
  const int*   es    = (const int*)d_in[2];
  const float* msgW1 = (const float*)d_in[6];
  const float* msgb1 = (const float*)d_in[7];
  const float* msgW2 = (const float*)d_in[8];
  const float* msgb2 = (const float*)d_in[9];
  const float* oW1   = (const float*)d_in[10];
  const float* ob1   = (const float*)d_in[11];
  const float* oW2   = (const float*)d_in[12];
  const float* ob2   = (const float*)d_in[13];
  const float* oW3   = (const float*)d_in[14];
  const float* ob3   = (const float*)d_in[15];
  const float* geWi  = (const float*)d_in[16];
  const float* gebi  = (const float*)d_in[17];
  const float* geWh  = (const float*)d_in[18];
  const float* gebh  = (const float*)d_in[19];
  const float* gnWi  = (const float*)d_in[20];
  const float* gnbi  = (const float*)d_in[21];
  const float* gnWh  = (const float*)d_in[22];
  const float* gnbh  = (const float*)d_in[23];
  float* out = (float*)d_out;

  char* p = (char*)d_ws;
  bf16*  hed   = (bf16*)p;   p += (size_t)NE * 4096 * 2;   // 8.1 MB, h_edge bf16
  float* xf    = (float*)p;  p += 65536 * 4;
  bf16*  xb    = (bf16*)p;   p += 65536 * 2;
  float* hnode = (float*)p;  p += 196608 * 4;
  bf16*  B1sw  = (bf16*)p;   p += 12288 * 2;
  bf16*  B2sw  = (bf16*)p;   p += 12288 * 2;
  bf16*  GIsw  = (bf16*)p;   p += 12288 * 2;
  bf16*  GHsw  = (bf16*)p;   p += 12288 * 2;

  prep_weights<<<48, 256, 0, stream>>>(msgW1, msgW2, geWi, geWh, B1sw, B2sw, GIsw, GHsw);

  for (int t = 0; t < NTT; t++) {
    if (t < NSTEP) copy_x<<<256, 256, 0, stream>>>(x, xf, xb, t);
    edge_step<<<NE, 256, 0, stream>>>(xb, es, z, B1sw, B2sw, msgb1, msgb2,
                                      GIsw, GHsw, gebi, gebh, hed, t);
    node_kernel<<<512, 256, 0, stream>>>(x, hed, xf, xb, hnode,
                                         gnWi, gnbi, gnWh, gnbh,
                                         oW1, ob1, oW2, ob2, oW3, ob3,
                                         out, t, t > 0 ? 1 : 0);
  }
}

// Round 7
// 658.180 us; speedup vs baseline: 1.6188x; 1.6188x over previous
//
#include <hip/hip_runtime.h>
#include <hip/hip_bf16.h>

// Problem dims
#define NNODE 32
#define NB    64
#define NDIM  32
#define NSTEP 8
#define NE    992
#define NTT   16

typedef __bf16 bf16;
typedef __attribute__((ext_vector_type(8))) __bf16 bf16x8;
typedef __attribute__((ext_vector_type(4))) __bf16 bf16x4;
typedef __attribute__((ext_vector_type(4))) float  f32x4;

__device__ __forceinline__ f32x4 mfma_bf16(bf16x8 a, bf16x8 b, f32x4 c) {
  return __builtin_amdgcn_mfma_f32_16x16x32_bf16(a, b, c, 0, 0, 0);
}
__device__ __forceinline__ float sigm(float x) { return 1.0f / (1.0f + __expf(-x)); }
__device__ __forceinline__ float tanh_f(float x) {
  x = fminf(fmaxf(x, -15.0f), 15.0f);
  float e = __expf(2.0f * x);
  return (e - 1.0f) / (e + 1.0f);
}

// ---------------------------------------------------------------------------
// Swizzle all weights into MFMA B-fragment bf16 order (round-3 validated).
// ---------------------------------------------------------------------------
__global__ void prep_weights(
    const float* __restrict__ msgW1, const float* __restrict__ msgW2,
    const float* __restrict__ geWi,  const float* __restrict__ geWh,
    const float* __restrict__ gnWi,  const float* __restrict__ gnWh,
    const float* __restrict__ oW1,   const float* __restrict__ oW2,
    const float* __restrict__ oW3,
    bf16* __restrict__ B1, bf16* __restrict__ B2,
    bf16* __restrict__ GI, bf16* __restrict__ GH,
    bf16* __restrict__ GN,
    bf16* __restrict__ OW1s, bf16* __restrict__ OW2s, bf16* __restrict__ OW3s) {
  int u = blockIdx.x * 256 + threadIdx.x;
  if (u < 12288) {
    int k = u >> 12, i = (u >> 6) & 63, h = u & 63;
    int kf = i >> 5, quad = (i >> 3) & 3, j = i & 7;
    int nn = k * 64 + h, nt = nn >> 4, lane = quad * 16 + (nn & 15);
    int slot = ((nt * 2 + kf) * 64 + lane) * 8 + j;
    B1[slot] = (bf16)msgW1[u];
    GI[slot] = (bf16)geWi[u];
    GH[slot] = (bf16)geWh[u];
    int ntl = h >> 4, lane2 = quad * 16 + (h & 15);
    int slot2 = k * 4096 + ((ntl * 2 + kf) * 64 + lane2) * 8 + j;
    B2[slot2] = (bf16)msgW2[u];
  } else if (u < 39936) {
    int v = u - 12288;
    int kk = v / 9216, rem = v % 9216, i = rem / 96, h = rem % 96;
    int kf = i >> 5, loc = i & 31, quad = loc >> 3, j = loc & 7;
    int nn = kk * 96 + h, nt = nn >> 4, lane = quad * 16 + (nn & 15);
    int slot = ((nt * 3 + kf) * 64 + lane) * 8 + j;
    GN[slot]         = (bf16)gnWi[v];
    GN[27648 + slot] = (bf16)gnWh[v];
  } else if (u < 46080) {
    int v = u - 39936; int i = v >> 6, h = v & 63;
    int kf = i >> 5, loc = i & 31, quad = loc >> 3, j = loc & 7;
    int nt = h >> 4, lane = quad * 16 + (h & 15);
    OW1s[((nt * 3 + kf) * 64 + lane) * 8 + j] = (bf16)oW1[v];
  } else if (u < 50176) {
    int v = u - 46080; int i = v >> 6, h = v & 63;
    int kf = i >> 5, quad = (i >> 3) & 3, j = i & 7;
    int nt = h >> 4, lane = quad * 16 + (h & 15);
    OW2s[((nt * 2 + kf) * 64 + lane) * 8 + j] = (bf16)oW2[v];
  } else if (u < 52224) {
    int v = u - 50176; int i = v >> 5, h = v & 31;
    int kf = i >> 5, quad = (i >> 3) & 3, j = i & 7;
    int nt = h >> 4, lane = quad * 16 + (h & 15);
    OW3s[((nt * 2 + kf) * 64 + lane) * 8 + j] = (bf16)oW3[v];
  }
}

// Initial input (t=0) into xf (fp32) + xb (bf16), layout [n][b][d].
__global__ void copy_x(const float* __restrict__ x, float* __restrict__ xf,
                       bf16* __restrict__ xb) {
  int u = blockIdx.x * 256 + threadIdx.x;  // 65536
  int n = u >> 11, b = (u >> 5) & 63, d = u & 31;
  float v = x[((b * 32 + n) * 32 + d) * 8 + 0];
  xf[u] = v;
  xb[u] = (bf16)v;
}

// ---------------------------------------------------------------------------
// Edge step v3: TWO edges per block (496 blocks). Each weight fragment load
// feeds 4 MFMAs. Biases+z staged in LDS. h_edge bf16 in global.
// ---------------------------------------------------------------------------
__global__ __launch_bounds__(256, 2) void edge_step(
    const bf16* __restrict__ xb, const int* __restrict__ es,
    const float* __restrict__ z,
    const bf16* __restrict__ B1, const bf16* __restrict__ B2,
    const float* __restrict__ mb1, const float* __restrict__ mb2,
    const bf16* __restrict__ GI, const bf16* __restrict__ GH,
    const float* __restrict__ gbi, const float* __restrict__ gbh,
    bf16* __restrict__ hed, int t) {
  __shared__ __align__(16) char scrbuf[51200];
  __shared__ float zL[2][64][3];
  __shared__ float biasL[768];  // mb1 | mb2 | gbi | gbh (192 each)
  bf16 (*A)[64][72]   = (bf16(*)[64][72])scrbuf;    // inputs / mix / state
  bf16 (*A2)[64][200] = (bf16(*)[64][200])scrbuf;   // h1 (aliases A)

  int e0 = blockIdx.x * 2, tid = threadIdx.x;
  int c0_ = es[e0],     r0 = es[NE + e0];
  int c1_ = es[e0 + 1], r1 = es[NE + e0 + 1];
  for (int u = tid; u < 768; u += 256)
    biasL[u] = (u < 192) ? mb1[u] : (u < 384) ? mb2[u - 192]
             : (u < 576) ? gbi[u - 384] : gbh[u - 576];
  for (int u = tid; u < 384; u += 256) {
    int pe = u / 192, rem = u % 192, b = rem / 3, k = rem % 3;
    zL[pe][b][k] = z[(b * NE + e0 + pe) * 3 + k];
  }
  for (int u = tid; u < 1024; u += 256) {
    int pe = u >> 9, c = u & 511;
    int b = c >> 3, i8 = c & 7;
    int nrow = pe ? r1 : r0, ncol = pe ? c1_ : c0_;
    const bf16* src = (i8 < 4) ? (xb + nrow * 2048 + b * 32 + i8 * 8)
                               : (xb + ncol * 2048 + b * 32 + (i8 - 4) * 8);
    *(bf16x8*)&A[pe][b][i8 * 8] = *(const bf16x8*)src;
  }
  __syncthreads();
  int wv = tid >> 6, ln = tid & 63, quad = ln >> 4, l16 = ln & 15;
  int m = wv * 16 + l16;
  bf16x8 af[2][2];
#pragma unroll
  for (int pe = 0; pe < 2; pe++)
#pragma unroll
    for (int kf = 0; kf < 2; kf++)
      af[pe][kf] = *(const bf16x8*)&A[pe][m][kf * 32 + quad * 8];
  __syncthreads();  // A dead -> A2 may overwrite
  // ---- layer 1: [64x64] @ [64x192], 2 edges ----
  f32x4 acc[2][12];
#pragma unroll
  for (int pe = 0; pe < 2; pe++)
#pragma unroll
    for (int q = 0; q < 12; q++) { f32x4 zz = {0.f,0.f,0.f,0.f}; acc[pe][q] = zz; }
#pragma unroll
  for (int nt = 0; nt < 12; nt++) {
    bf16x8 w0 = *(const bf16x8*)&B1[(nt * 2 + 0) * 512 + ln * 8];
    bf16x8 w1 = *(const bf16x8*)&B1[(nt * 2 + 1) * 512 + ln * 8];
#pragma unroll
    for (int pe = 0; pe < 2; pe++) {
      acc[pe][nt] = mfma_bf16(af[pe][0], w0, acc[pe][nt]);
      acc[pe][nt] = mfma_bf16(af[pe][1], w1, acc[pe][nt]);
    }
  }
#pragma unroll
  for (int nt = 0; nt < 12; nt++) {
    int n = nt * 16 + l16;
    float bias = biasL[n];
#pragma unroll
    for (int pe = 0; pe < 2; pe++)
#pragma unroll
      for (int r = 0; r < 4; r++) {
        float v = acc[pe][nt][r] + bias;
        A2[pe][wv * 16 + quad * 4 + r][n] = (bf16)(v > 0.f ? v : 0.f);
      }
  }
  __syncthreads();
  bf16x8 a2[2][3][2];
#pragma unroll
  for (int pe = 0; pe < 2; pe++)
#pragma unroll
    for (int kt = 0; kt < 3; kt++)
#pragma unroll
      for (int kf = 0; kf < 2; kf++)
        a2[pe][kt][kf] = *(const bf16x8*)&A2[pe][m][kt * 64 + kf * 32 + quad * 8];
  __syncthreads();  // A2 dead -> A (mix/state) may overwrite
  // ---- layer 2: per-type [64x64] blocks ----
  f32x4 acc2[2][12];
#pragma unroll
  for (int pe = 0; pe < 2; pe++)
#pragma unroll
    for (int q = 0; q < 12; q++) { f32x4 zz = {0.f,0.f,0.f,0.f}; acc2[pe][q] = zz; }
#pragma unroll
  for (int kt = 0; kt < 3; kt++)
#pragma unroll
    for (int nt = 0; nt < 4; nt++) {
      bf16x8 w0 = *(const bf16x8*)&B2[kt * 4096 + (nt * 2 + 0) * 512 + ln * 8];
      bf16x8 w1 = *(const bf16x8*)&B2[kt * 4096 + (nt * 2 + 1) * 512 + ln * 8];
#pragma unroll
      for (int pe = 0; pe < 2; pe++) {
        acc2[pe][kt * 4 + nt] = mfma_bf16(a2[pe][kt][0], w0, acc2[pe][kt * 4 + nt]);
        acc2[pe][kt * 4 + nt] = mfma_bf16(a2[pe][kt][1], w1, acc2[pe][kt * 4 + nt]);
      }
    }
  // ---- mix with z, /K -> write into A (own-wave rows) ----
#pragma unroll
  for (int pe = 0; pe < 2; pe++)
#pragma unroll
    for (int r = 0; r < 4; r++) {
      int b = wv * 16 + quad * 4 + r;
      float z0 = zL[pe][b][0], z1 = zL[pe][b][1], z2 = zL[pe][b][2];
#pragma unroll
      for (int nt = 0; nt < 4; nt++) {
        int o = nt * 16 + l16;
        float h0 = acc2[pe][nt][r]     + biasL[192 + o];       h0 = h0 > 0.f ? h0 : 0.f;
        float h1 = acc2[pe][4 + nt][r] + biasL[192 + 64 + o];  h1 = h1 > 0.f ? h1 : 0.f;
        float h2 = acc2[pe][8 + nt][r] + biasL[192 + 128 + o]; h2 = h2 > 0.f ? h2 : 0.f;
        A[pe][b][o] = (bf16)((h0 * z0 + h1 * z1 + h2 * z2) * (1.0f / 3.0f));
      }
    }
  if (t > 0) {
    __syncthreads();
    // ---- edge GRU: mix (LDS A) + old state (global hed) ----
    bf16x8 ai[2][2], ah[2][2];
#pragma unroll
    for (int pe = 0; pe < 2; pe++) {
      const bf16* hrow = hed + (e0 + pe) * 4096 + m * 64;
#pragma unroll
      for (int kf = 0; kf < 2; kf++) {
        ai[pe][kf] = *(const bf16x8*)&A[pe][m][kf * 32 + quad * 8];
        ah[pe][kf] = *(const bf16x8*)(hrow + kf * 32 + quad * 8);
      }
    }
    f32x4 gri[2][8], gni[2][4], gnh[2][4];
#pragma unroll
    for (int pe = 0; pe < 2; pe++) {
#pragma unroll
      for (int q = 0; q < 8; q++) { f32x4 zz = {0.f,0.f,0.f,0.f}; gri[pe][q] = zz; }
#pragma unroll
      for (int q = 0; q < 4; q++) { f32x4 zz = {0.f,0.f,0.f,0.f}; gni[pe][q] = zz; gnh[pe][q] = zz; }
    }
#pragma unroll
    for (int nt = 0; nt < 8; nt++) {   // r,i gates: gi+gh merged
      bf16x8 wi0 = *(const bf16x8*)&GI[(nt * 2 + 0) * 512 + ln * 8];
      bf16x8 wi1 = *(const bf16x8*)&GI[(nt * 2 + 1) * 512 + ln * 8];
      bf16x8 wh0 = *(const bf16x8*)&GH[(nt * 2 + 0) * 512 + ln * 8];
      bf16x8 wh1 = *(const bf16x8*)&GH[(nt * 2 + 1) * 512 + ln * 8];
#pragma unroll
      for (int pe = 0; pe < 2; pe++) {
        gri[pe][nt] = mfma_bf16(ai[pe][0], wi0, gri[pe][nt]);
        gri[pe][nt] = mfma_bf16(ai[pe][1], wi1, gri[pe][nt]);
        gri[pe][nt] = mfma_bf16(ah[pe][0], wh0, gri[pe][nt]);
        gri[pe][nt] = mfma_bf16(ah[pe][1], wh1, gri[pe][nt]);
      }
    }
#pragma unroll
    for (int nt = 8; nt < 12; nt++) {  // n gate: separate
      bf16x8 wi0 = *(const bf16x8*)&GI[(nt * 2 + 0) * 512 + ln * 8];
      bf16x8 wi1 = *(const bf16x8*)&GI[(nt * 2 + 1) * 512 + ln * 8];
      bf16x8 wh0 = *(const bf16x8*)&GH[(nt * 2 + 0) * 512 + ln * 8];
      bf16x8 wh1 = *(const bf16x8*)&GH[(nt * 2 + 1) * 512 + ln * 8];
#pragma unroll
      for (int pe = 0; pe < 2; pe++) {
        gni[pe][nt - 8] = mfma_bf16(ai[pe][0], wi0, gni[pe][nt - 8]);
        gni[pe][nt - 8] = mfma_bf16(ai[pe][1], wi1, gni[pe][nt - 8]);
        gnh[pe][nt - 8] = mfma_bf16(ah[pe][0], wh0, gnh[pe][nt - 8]);
        gnh[pe][nt - 8] = mfma_bf16(ah[pe][1], wh1, gnh[pe][nt - 8]);
      }
    }
#pragma unroll
    for (int pe = 0; pe < 2; pe++)
#pragma unroll
      for (int r = 0; r < 4; r++) {
        int b = wv * 16 + quad * 4 + r;
#pragma unroll
        for (int nt = 0; nt < 4; nt++) {
          int o = nt * 16 + l16;
          float xr = gri[pe][nt][r]     + biasL[384 + o]      + biasL[576 + o];
          float xi = gri[pe][4 + nt][r] + biasL[384 + 64 + o] + biasL[576 + 64 + o];
          float xn = gni[pe][nt][r] + biasL[384 + 128 + o];
          float hn = gnh[pe][nt][r] + biasL[576 + 128 + o];
          float rg = sigm(xr);
          float ig = sigm(xi);
          float ng = tanh_f(xn + rg * hn);
          float hv = (float)hed[(e0 + pe) * 4096 + b * 64 + o];
          A[pe][b][o] = (bf16)((1.0f - ig) * ng + ig * hv);
        }
      }
  }
  __syncthreads();
  // coalesced writeback of new state
  for (int u = tid; u < 1024; u += 256) {
    int pe = u >> 9, c = u & 511;
    int b = c >> 3, j = c & 7;
    *(bf16x8*)(hed + (e0 + pe) * 4096 + b * 64 + j * 8) = *(const bf16x8*)&A[pe][b][j * 8];
  }
}

// ---------------------------------------------------------------------------
// Node kernel (round-3 validated MFMA version, bf16 hed): scatter-mean agg +
// node GRU (MFMA) + 3-layer out-MLP. Also prepares next step's input.
// ---------------------------------------------------------------------------
__global__ __launch_bounds__(256) void node_kernel(
    const float* __restrict__ x, const bf16* __restrict__ hed,
    float* __restrict__ xf, bf16* __restrict__ xb, float* __restrict__ hnode,
    const bf16* __restrict__ GN,
    const float* __restrict__ gnbi, const float* __restrict__ gnbh,
    const bf16* __restrict__ OW1, const float* __restrict__ ob1,
    const bf16* __restrict__ OW2, const float* __restrict__ ob2,
    const bf16* __restrict__ OW3, const float* __restrict__ ob3,
    float* __restrict__ out, int t) {
  __shared__ float aggf[16][64];
  __shared__ float xinf[16][32];
  __shared__ float hvf[16][96];
  __shared__ __align__(16) bf16 c0b[16][112];
  __shared__ __align__(16) bf16 hvb[16][112];
  __shared__ float gsum[2][16][290];
  __shared__ __align__(16) bf16 cnb[16][112];
  __shared__ __align__(16) bf16 s1b[16][112];
  __shared__ __align__(16) bf16 s2b[16][112];
  int nq = blockIdx.x, n = nq >> 2, q = nq & 3;
  int tid = threadIdx.x;
  // --- aggregation: mean over node n's 31 contiguous edges (bf16x4 loads) ---
  {
    int r = tid >> 4, o4 = tid & 15;
    const bf16x4* bp = (const bf16x4*)hed + (size_t)n * 31 * 1024 + (q * 16 + r) * 16 + o4;
    float sx = 0.f, sy = 0.f, sz = 0.f, sw = 0.f;
#pragma unroll
    for (int e2 = 0; e2 < 31; e2++) {
      bf16x4 v = bp[e2 * 1024];
      sx += (float)v[0]; sy += (float)v[1]; sz += (float)v[2]; sw += (float)v[3];
    }
    const float inv = 1.0f / 31.0f;
    sx *= inv; sy *= inv; sz *= inv; sw *= inv;
    int o = o4 * 4;
    aggf[r][o] = sx; aggf[r][o + 1] = sy; aggf[r][o + 2] = sz; aggf[r][o + 3] = sw;
    c0b[r][32 + o] = (bf16)sx; c0b[r][33 + o] = (bf16)sy;
    c0b[r][34 + o] = (bf16)sz; c0b[r][35 + o] = (bf16)sw;
  }
  // --- x_in from xf (prepared by previous step / copy_x) ---
  if (tid < 128) {
    int r = tid >> 3, d0 = (tid & 7) * 4;
    int b = q * 16 + r;
#pragma unroll
    for (int k = 0; k < 4; k++) {
      float v = xf[n * 2048 + b * 32 + d0 + k];
      xinf[r][d0 + k] = v;
      c0b[r][d0 + k] = (bf16)v;
    }
  }
  // --- h_node old ---
  if (t > 0) {
    int r = tid >> 4, cb = (tid & 15) * 6;
    int row = n * 64 + q * 16 + r;
#pragma unroll
    for (int k = 0; k < 6; k++) {
      float v = hnode[row * 96 + cb + k];
      hvf[r][cb + k] = v;
      hvb[r][cb + k] = (bf16)v;
    }
  }
  __syncthreads();
  int wv = tid >> 6, ln = tid & 63, quad = ln >> 4, l16 = ln & 15;
  // --- node GRU gates via MFMA ---
  if (t > 0) {
    int mat = wv >> 1, sel = wv & 1;
    const bf16(*Ab)[112] = mat ? hvb : c0b;
    bf16x8 af[3];
#pragma unroll
    for (int kf = 0; kf < 3; kf++)
      af[kf] = *(const bf16x8*)&Ab[l16][kf * 32 + quad * 8];
    const bf16* W = GN + mat * 27648;
    f32x4 accn[9];
#pragma unroll
    for (int q2 = 0; q2 < 9; q2++) { f32x4 zz = {0.f,0.f,0.f,0.f}; accn[q2] = zz; }
#pragma unroll
    for (int nt2 = 0; nt2 < 9; nt2++) {
      int nt = sel * 9 + nt2;
#pragma unroll
      for (int kf = 0; kf < 3; kf++) {
        bf16x8 bfrag = *(const bf16x8*)&W[((nt * 3 + kf) * 64 + ln) * 8];
        accn[nt2] = mfma_bf16(af[kf], bfrag, accn[nt2]);
      }
    }
#pragma unroll
    for (int nt2 = 0; nt2 < 9; nt2++) {
      int col = (sel * 9 + nt2) * 16 + l16;
#pragma unroll
      for (int rr = 0; rr < 4; rr++)
        gsum[mat][quad * 4 + rr][col] = accn[nt2][rr];
    }
  }
  __syncthreads();
  // --- gates elementwise -> cnb / hnode ---
  {
    int r = tid >> 4, cb = (tid & 15) * 6;
    int row = n * 64 + q * 16 + r;
#pragma unroll
    for (int k = 0; k < 6; k++) {
      int c = cb + k;
      float v;
      if (t > 0) {
        float xr = gsum[0][r][c] + gnbi[c] + gsum[1][r][c] + gnbh[c];
        float xi = gsum[0][r][96 + c] + gnbi[96 + c] + gsum[1][r][96 + c] + gnbh[96 + c];
        float xn = gsum[0][r][192 + c] + gnbi[192 + c];
        float hn = gsum[1][r][192 + c] + gnbh[192 + c];
        float rg = sigm(xr);
        float ig = sigm(xi);
        float ng = tanh_f(xn + rg * hn);
        v = (1.0f - ig) * ng + ig * hvf[r][c];
      } else {
        v = (c < 32) ? xinf[r][c] : aggf[r][c - 32];
      }
      cnb[r][c] = (bf16)v;
      hnode[row * 96 + c] = v;
    }
  }
  __syncthreads();
  // --- h1 = relu(cn @ oW1 + b1) ---
  {
    bf16x8 af[3];
#pragma unroll
    for (int kf = 0; kf < 3; kf++)
      af[kf] = *(const bf16x8*)&cnb[l16][kf * 32 + quad * 8];
    f32x4 accn = {0.f, 0.f, 0.f, 0.f};
#pragma unroll
    for (int kf = 0; kf < 3; kf++) {
      bf16x8 bfrag = *(const bf16x8*)&OW1[((wv * 3 + kf) * 64 + ln) * 8];
      accn = mfma_bf16(af[kf], bfrag, accn);
    }
    int col = wv * 16 + l16;
    float bias = ob1[col];
#pragma unroll
    for (int rr = 0; rr < 4; rr++) {
      float vv = accn[rr] + bias;
      s1b[quad * 4 + rr][col] = (bf16)(vv > 0.f ? vv : 0.f);
    }
  }
  __syncthreads();
  // --- h2 = relu(h1 @ oW2 + b2) ---
  {
    bf16x8 af[2];
#pragma unroll
    for (int kf = 0; kf < 2; kf++)
      af[kf] = *(const bf16x8*)&s1b[l16][kf * 32 + quad * 8];
    f32x4 accn = {0.f, 0.f, 0.f, 0.f};
#pragma unroll
    for (int kf = 0; kf < 2; kf++) {
      bf16x8 bfrag = *(const bf16x8*)&OW2[((wv * 2 + kf) * 64 + ln) * 8];
      accn = mfma_bf16(af[kf], bfrag, accn);
    }
    int col = wv * 16 + l16;
    float bias = ob2[col];
#pragma unroll
    for (int rr = 0; rr < 4; rr++) {
      float vv = accn[rr] + bias;
      s2b[quad * 4 + rr][col] = (bf16)(vv > 0.f ? vv : 0.f);
    }
  }
  __syncthreads();
  // --- delta + outputs + next-step input ---
  if (wv < 2) {
    bf16x8 af[2];
#pragma unroll
    for (int kf = 0; kf < 2; kf++)
      af[kf] = *(const bf16x8*)&s2b[l16][kf * 32 + quad * 8];
    f32x4 accn = {0.f, 0.f, 0.f, 0.f};
#pragma unroll
    for (int kf = 0; kf < 2; kf++) {
      bf16x8 bfrag = *(const bf16x8*)&OW3[((wv * 2 + kf) * 64 + ln) * 8];
      accn = mfma_bf16(af[kf], bfrag, accn);
    }
    int d = wv * 16 + l16;
    float bias = ob3[d];
#pragma unroll
    for (int rr = 0; rr < 4; rr++) {
      int r = quad * 4 + rr;
      int b = q * 16 + r;
      float xm = xinf[r][d] + accn[rr] + bias;
      int base = (b * 32 + n) * 32 + d;
      out[524288 + base * 16 + t] = xm;
      out[1572864 + base * 16 + t] = xm;
      if (t >= NSTEP) out[base * 8 + (t - NSTEP)] = xm;
      float vnext = (t + 1 < NSTEP) ? x[base * 8 + (t + 1)] : xm;
      xf[n * 2048 + b * 32 + d] = vnext;
      xb[n * 2048 + b * 32 + d] = (bf16)vnext;
    }
  }
}

extern "C" void kernel_launch(void* const* d_in, const int* in_sizes, int n_in,
                              void* d_out, int out_size, void* d_ws, size_t ws_size,
                              hipStream_t stream) {
  const float* x     = (const float*)d_in[0];
  const float* z     = (const float*)d_in[1];
  const int*   es    = (const int*)d_in[2];
  const float* msgW1 = (const float*)d_in[6];
  const float* msgb1 = (const float*)d_in[7];
  const float* msgW2 = (const float*)d_in[8];
  const float* msgb2 = (const float*)d_in[9];
  const float* oW1   = (const float*)d_in[10];
  const float* ob1   = (const float*)d_in[11];
  const float* oW2   = (const float*)d_in[12];
  const float* ob2   = (const float*)d_in[13];
  const float* oW3   = (const float*)d_in[14];
  const float* ob3   = (const float*)d_in[15];
  const float* geWi  = (const float*)d_in[16];
  const float* gebi  = (const float*)d_in[17];
  const float* geWh  = (const float*)d_in[18];
  const float* gebh  = (const float*)d_in[19];
  const float* gnWi  = (const float*)d_in[20];
  const float* gnbi  = (const float*)d_in[21];
  const float* gnWh  = (const float*)d_in[22];
  const float* gnbh  = (const float*)d_in[23];
  float* out = (float*)d_out;

  char* p = (char*)d_ws;
  bf16*  hed   = (bf16*)p;   p += (size_t)NE * 4096 * 2;   // 8.1 MB
  float* xf    = (float*)p;  p += 65536 * 4;
  bf16*  xb    = (bf16*)p;   p += 65536 * 2;
  float* hnode = (float*)p;  p += 196608 * 4;
  bf16*  B1sw  = (bf16*)p;   p += 12288 * 2;
  bf16*  B2sw  = (bf16*)p;   p += 12288 * 2;
  bf16*  GIsw  = (bf16*)p;   p += 12288 * 2;
  bf16*  GHsw  = (bf16*)p;   p += 12288 * 2;
  bf16*  GNsw  = (bf16*)p;   p += 55296 * 2;
  bf16*  OW1s  = (bf16*)p;   p += 6144 * 2;
  bf16*  OW2s  = (bf16*)p;   p += 4096 * 2;
  bf16*  OW3s  = (bf16*)p;   p += 2048 * 2;

  prep_weights<<<204, 256, 0, stream>>>(msgW1, msgW2, geWi, geWh, gnWi, gnWh,
                                        oW1, oW2, oW3,
                                        B1sw, B2sw, GIsw, GHsw, GNsw,
                                        OW1s, OW2s, OW3s);
  copy_x<<<256, 256, 0, stream>>>(x, xf, xb);

  for (int t = 0; t < NTT; t++) {
    edge_step<<<NE / 2, 256, 0, stream>>>(xb, es, z, B1sw, B2sw, msgb1, msgb2,
                                          GIsw, GHsw, gebi, gebh, hed, t);
    node_kernel<<<128, 256, 0, stream>>>(x, hed, xf, xb, hnode, GNsw, gnbi, gnbh,
                                         OW1s, ob1, OW2s, ob2, OW3s, ob3,
                                         out, t);
  }
}